// Round 10
// baseline (909.960 us; speedup 1.0000x reference)
//
#include <hip/hip_runtime.h>

typedef unsigned short ushort_t;
typedef __bf16 bf16x8 __attribute__((ext_vector_type(8)));
typedef float f32x4 __attribute__((ext_vector_type(4)));
typedef float f32x16 __attribute__((ext_vector_type(16)));

#define PACK_W_ELEMS (8*18*4*512)          // 294912 bf16 per LSTM: [wave8][kt18][g4][512]
#define HEAD_ELEMS   (9*512)               // 1 n-tile x 9 k-tiles (16x16x32 layout)
#define PACK_TOTAL   (4*PACK_W_ELEMS + 2*HEAD_ELEMS)
#define FLAG_OFS     PACK_TOTAL            // ushort index of int dtype flag

__device__ __forceinline__ float bf2f(ushort_t u){ return __uint_as_float(((unsigned)u)<<16); }
__device__ __forceinline__ ushort_t f2bf(float f){
  __bf16 h = (__bf16)f;                    // HW RTNE convert (values bounded)
  return *(ushort_t*)&h;
}
__device__ __forceinline__ float rcp_(float x){ return __builtin_amdgcn_rcpf(x); }

__device__ __forceinline__ int sniff_f32(const ushort_t* w){
  int f32 = 0;
  #pragma unroll
  for (int i = 0; i < 32; ++i){
    float f = bf2f(w[2*i]);
    if (!(f > -8.f && f < 8.f)) f32 = 1;
  }
  return f32;
}
__device__ __forceinline__ float ldin(const ushort_t* p, int i, int f32){
  return f32 ? ((const float*)p)[i] : bf2f(p[i]);
}
__device__ __forceinline__ ushort_t ldw(const ushort_t* p, int i, int f32){
  return f32 ? f2bf(((const float*)p)[i]) : p[i];
}

// ---------------- pack kernel ----------------
// LSTM pack (32x32x16 B-frags): [wave8][kt18][g4][512]; B tile (wv,kt,g):
// element (lane,j): col n = g*256 + wv*32 + (lane&31); k = kt*16 + (lane>>5)*8 + j.
// K map: k<256 Whh[n][k]; 256..259 Wih; k==260 bias (bih+bhh); else 0.
// Head packs unchanged (16x16x32 layout).
struct PackArgs {
  const ushort_t* wih[4]; const ushort_t* whh[4];
  const ushort_t* bih[4]; const ushort_t* bhh[4];
  const ushort_t* fcsp_w; const ushort_t* fcsp_b;
  const ushort_t* fccr_w; const ushort_t* fccr_b;
  const ushort_t* emb_w;  const ushort_t* emb_b;
  ushort_t* ws;
};

__global__ void pack_kernel(PackArgs a){
  const int f32 = sniff_f32(a.whh[0]);
  int idx = blockIdx.x*256 + threadIdx.x;
  if (blockIdx.x == 0 && threadIdx.x == 0) *(int*)(a.ws + FLAG_OFS) = f32;
  const int total_w = 4*PACK_W_ELEMS;
  if (idx < total_w){
    int l = idx / PACK_W_ELEMS;
    int r = idx % PACK_W_ELEMS;
    int j = r & 7;
    int lane = (r>>3) & 63;
    int tile = r >> 9;            // (wv*18 + kt)*4 + g
    int g = tile & 3;
    int kt = (tile >> 2) % 18;
    int wv = tile / 72;
    int n = g*256 + wv*32 + (lane & 31);
    int k = kt*16 + ((lane>>5)<<3) + j;
    ushort_t v = 0;
    if (k < 256)       v = ldw(a.whh[l], n*256 + k, f32);
    else if (k < 260)  v = ldw(a.wih[l], n*4 + (k-256), f32);
    else if (k == 260) v = f2bf(ldin(a.bih[l], n, f32) + ldin(a.bhh[l], n, f32));
    a.ws[l*PACK_W_ELEMS + r] = v;
    return;
  }
  idx -= total_w;
  if (idx < 2*HEAD_ELEMS){
    int which = idx / HEAD_ELEMS;           // 0 = speed, 1 = cross
    int r = idx % HEAD_ELEMS;
    int j = r & 7; int lane = (r>>3)&63; int kt = r>>9;
    int n = lane & 15; int k = kt*32 + ((lane>>4)<<3) + j;
    ushort_t v = 0;
    if (which == 0){
      if (n < 4){
        if (k < 256)       v = ldw(a.fcsp_w, n*256 + k, f32);
        else if (k == 260) v = f2bf(ldin(a.fcsp_b, n, f32));
      }
    } else {
      if (n < 4){
        if (k < 256)       v = ldw(a.emb_w, n*256 + k, f32);
        else if (k == 260) v = f2bf(ldin(a.emb_b, n, f32));
      } else if (n < 6){
        if (k < 256)       v = ldw(a.fccr_w, (n-4)*256 + k, f32);
        else if (k == 260) v = f2bf(ldin(a.fccr_b, n-4, f32));
      }
    }
    a.ws[total_w + idx] = v;
  }
}

// ---------------- device helpers for the main kernel ----------------
// A-pack LDS layout: [mt(2)][kt(18)][512]; element (lane,j) of tile (mt,kt) =
// A[row = mt*32 + (lane&31)][k = kt*16 + (lane>>5)*8 + j].
// 32x32x16 gate GEMM: acc[2][4] f32x16 (128 AGPR), kt-ascending accumulation.
#define PRE4(bw, s0, s1, s2, s3)                \
  bf16x8 s0 = *(const bf16x8*)&(bw)[0*512];     \
  bf16x8 s1 = *(const bf16x8*)&(bw)[1*512];     \
  bf16x8 s2 = *(const bf16x8*)&(bw)[2*512];     \
  bf16x8 s3 = *(const bf16x8*)&(bw)[3*512];

__device__ __forceinline__ void gate_gemm(const ushort_t* __restrict__ Aln,   // ApX + lane*8
                                          const ushort_t* __restrict__ bw,   // wave pack + lane*8
                                          f32x16 (&acc)[2][4],
                                          bf16x8 p0, bf16x8 p1, bf16x8 p2, bf16x8 p3){
  #pragma unroll
  for (int i = 0; i < 2; ++i)
    #pragma unroll
    for (int j = 0; j < 4; ++j) acc[i][j] = (f32x16)(0.f);
  const ushort_t* bp = bw;
  #pragma unroll 1
  for (int kt = 0; kt < 18; ++kt){
    bf16x8 a0 = *(const bf16x8*)&Aln[(     kt)*512];
    bf16x8 a1 = *(const bf16x8*)&Aln[(18 + kt)*512];
    acc[0][0] = __builtin_amdgcn_mfma_f32_32x32x16_bf16(a0, p0, acc[0][0], 0, 0, 0);
    acc[1][0] = __builtin_amdgcn_mfma_f32_32x32x16_bf16(a1, p0, acc[1][0], 0, 0, 0);
    acc[0][1] = __builtin_amdgcn_mfma_f32_32x32x16_bf16(a0, p1, acc[0][1], 0, 0, 0);
    acc[1][1] = __builtin_amdgcn_mfma_f32_32x32x16_bf16(a1, p1, acc[1][1], 0, 0, 0);
    // prefetch next kt's 4 B tiles under the remaining MFMAs
    bf16x8 q0, q1, q2, q3;
    if (kt < 17){
      q0 = *(const bf16x8*)&bp[2048 + 0*512];
      q1 = *(const bf16x8*)&bp[2048 + 1*512];
      q2 = *(const bf16x8*)&bp[2048 + 2*512];
      q3 = *(const bf16x8*)&bp[2048 + 3*512];
    }
    acc[0][2] = __builtin_amdgcn_mfma_f32_32x32x16_bf16(a0, p2, acc[0][2], 0, 0, 0);
    acc[1][2] = __builtin_amdgcn_mfma_f32_32x32x16_bf16(a1, p2, acc[1][2], 0, 0, 0);
    acc[0][3] = __builtin_amdgcn_mfma_f32_32x32x16_bf16(a0, p3, acc[0][3], 0, 0, 0);
    acc[1][3] = __builtin_amdgcn_mfma_f32_32x32x16_bf16(a1, p3, acc[1][3], 0, 0, 0);
    if (kt < 17){ p0 = q0; p1 = q1; p2 = q2; p3 = q3; }
    bp += 2048;
  }
}

// gate nonlinearity + h writeback; gates in acc[mt][g]: 0=i,1=f,2=g,3=o, element reg.
// C/D layout: col = lane&31 (h-col = w*32 + col), row = (reg&3)+8*(reg>>2)+4*(lane>>5).
// Merged-division form (r9): 5 exp + 2 rcp per element.
__device__ __forceinline__ void gates_wb(f32x16 (&acc)[2][4], float (&cw)[2][16],
                                         ushort_t* __restrict__ Ap, int wbBase, int hi5){
  #pragma unroll
  for (int mt = 0; mt < 2; ++mt)
    #pragma unroll
    for (int reg = 0; reg < 16; ++reg){
      const float i_ = acc[mt][0][reg];
      const float f_ = acc[mt][1][reg];
      const float g_ = acc[mt][2][reg];
      const float o_ = acc[mt][3][reg];
      const float ei = __expf(-i_);
      const float ef = __expf(-f_);
      const float eg = __expf(-2.0f*g_);
      const float di = 1.0f + ei, df = 1.0f + ef;
      const float dg = 1.0f + eg, ng = 1.0f - eg;
      const float dig = di*dg;
      const float cn = (cw[mt][reg]*dig + ng*df) * rcp_(df*dig);
      const float eo = __expf(-o_);
      const float ec = __expf(-2.0f*cn);
      const float hn = (1.0f - ec) * rcp_((1.0f + eo)*(1.0f + ec));
      cw[mt][reg] = cn;
      const int rw = (reg&3) + 8*(reg>>2) + 4*hi5;
      Ap[mt*9216 + wbBase + rw*8] = f2bf(hn);
    }
}

// ---------------- main kernel: 256 blocks x 64 rows, 512 threads (8 waves) ----------------
// Round-9 structure; delta: gate GEMM on 32x32x16 MFMA (13% faster matrix pipe, half the
// MFMA instruction count). Heads remain 16x16x32 reading the remapped A-pack.
__global__ __launch_bounds__(512, 2) void pvlstm_main(
    const ushort_t* __restrict__ ws,
    const ushort_t* __restrict__ speed,
    const ushort_t* __restrict__ pos,
    void* __restrict__ outv)
{
  __shared__ ushort_t ApS[2*18*512];  // A-pack speed-enc / speed-dec (36 KB)
  __shared__ ushort_t ApP[2*18*512];  // A-pack pos-enc / cross-dec   (36 KB)
  __shared__ ushort_t xsS[64*64];     // staged speed inputs (8 KB)
  __shared__ ushort_t xsP[64*64];     // staged pos inputs   (8 KB)
  __shared__ float    ostS[64*64];    // speed outputs stage (16 KB)
  __shared__ float    ostC[64*32];    // crossing outputs stage (8 KB)

  const int f32   = *(const int*)(ws + FLAG_OFS);
  const int tid   = threadIdx.x;
  const int lane  = tid & 63;
  const int w     = tid >> 6;   // 0..7
  const int col16 = lane & 15;
  const int quad  = lane >> 4;
  const int c5    = lane & 31;
  const int hi5   = lane >> 5;
  const int brow0 = blockIdx.x * 64;
  // wb target: h-col C = w*32 + c5 -> ktA = C>>4, hiA = (C>>3)&1, jA = C&7
  const int wbBase = (w*2 + (c5>>4))*512 + ((c5>>3)&1)*256 + (lane & 7);

  ushort_t* outu = (ushort_t*)outv;
  float*    outf = (float*)outv;

  const ushort_t* headsp = ws + 4*PACK_W_ELEMS;
  const ushort_t* headcr = headsp + HEAD_ELEMS;
  const ushort_t* aS  = ApS + lane*8;
  const ushort_t* aP  = ApP + lane*8;
  const ushort_t* bwS  = ws + 0*PACK_W_ELEMS + (size_t)w*36864 + (size_t)lane*8;
  const ushort_t* bwP  = ws + 1*PACK_W_ELEMS + (size_t)w*36864 + (size_t)lane*8;
  const ushort_t* bwDS = ws + 2*PACK_W_ELEMS + (size_t)w*36864 + (size_t)lane*8;
  const ushort_t* bwDC = ws + 3*PACK_W_ELEMS + (size_t)w*36864 + (size_t)lane*8;

  float cwA[2][16], cwB[2][16];
  f32x16 acc[2][4];

  // ---- prologue: stage inputs, zero A-packs, bias column, x_sp(0) ----
  for (int i = tid; i < 4096; i += 512){
    int gi = (brow0 + (i>>6))*64 + (i&63);
    xsS[i] = f2bf(ldin(speed, gi, f32));
    xsP[i] = f2bf(ldin(pos,   gi, f32));
  }
  for (int i = tid; i < 2*18*512/2; i += 512){
    ((unsigned*)ApS)[i] = 0u; ((unsigned*)ApP)[i] = 0u;
  }
  #pragma unroll
  for (int mt = 0; mt < 2; ++mt)
    #pragma unroll
    for (int r = 0; r < 16; ++r){ cwA[mt][r] = 0.f; cwB[mt][r] = 0.f; }
  __syncthreads();
  if (tid < 64){
    // x block: row R = tid -> addr ((R>>5)*18 + 16)*512 + (R&31)*8 ; k=256..259 = j 0..3, bias j=4
    ushort_t* xpS = &ApS[((tid>>5)*18 + 16)*512 + (tid&31)*8];
    ushort_t* xpP = &ApP[((tid>>5)*18 + 16)*512 + (tid&31)*8];
    *(uint2*)xpS = *(const uint2*)&xsS[tid*64];    // x_sp(0)
    xpS[4] = (ushort_t)0x3f80;                     // bias 1.0 column
    xpP[4] = (ushort_t)0x3f80;
  }
  __syncthreads();

  // ================= encoders: sp (A) and po (B), interleaved =================
  for (int t = 0; t < 16; ++t){
    // R1: [preload B_sp] gates_po(t-1)+wb -> ApP ; x_po(t) -> ApP.k256 ; GEMM_sp(t)
    {
      PRE4(bwS, s0, s1, s2, s3)
      if (t > 0) gates_wb(acc, cwB, ApP, wbBase, hi5);
      if (tid < 64)
        *(uint2*)&ApP[((tid>>5)*18 + 16)*512 + (tid&31)*8] = *(const uint2*)&xsP[tid*64 + t*4];
      gate_gemm(aS, bwS, acc, s0, s1, s2, s3);
    }
    __syncthreads();
    // R2: [preload B_po] gates_sp(t)+wb -> ApS ; x_sp(t+1) -> ApS.k256 ; GEMM_po(t)
    {
      PRE4(bwP, s0, s1, s2, s3)
      gates_wb(acc, cwA, ApS, wbBase, hi5);
      if (t < 15 && tid < 64)
        *(uint2*)&ApS[((tid>>5)*18 + 16)*512 + (tid&31)*8] = *(const uint2*)&xsS[tid*64 + t*4 + 4];
      gate_gemm(aP, bwP, acc, s0, s1, s2, s3);
    }
    __syncthreads();
  }
  // ---- encoder epilogue: gates_po(15) (merged form); h0 = h_sp+h_po; c0 in regs ----
  #pragma unroll
  for (int mt = 0; mt < 2; ++mt)
    #pragma unroll
    for (int reg = 0; reg < 16; ++reg){
      const float i_ = acc[mt][0][reg];
      const float f_ = acc[mt][1][reg];
      const float g_ = acc[mt][2][reg];
      const float o_ = acc[mt][3][reg];
      const float ei = __expf(-i_);
      const float ef = __expf(-f_);
      const float eg = __expf(-2.0f*g_);
      const float di = 1.0f + ei, df = 1.0f + ef;
      const float dg = 1.0f + eg, ng = 1.0f - eg;
      const float dig = di*dg;
      const float cn = (cwB[mt][reg]*dig + ng*df) * rcp_(df*dig);
      const float eo = __expf(-o_);
      const float ec = __expf(-2.0f*cn);
      const float hn = (1.0f - ec) * rcp_((1.0f + eo)*(1.0f + ec));
      const float c0 = cwA[mt][reg] + cn;
      cwA[mt][reg] = c0; cwB[mt][reg] = c0;
      const int rw = (reg&3) + 8*(reg>>2) + 4*hi5;
      const int ad = mt*9216 + wbBase + rw*8;
      ushort_t h0 = f2bf(bf2f(ApS[ad]) + hn);    // h_sp(15) written in R2(15)
      ApS[ad] = h0; ApP[ad] = h0;
    }
  if (tid < 64){
    *(uint2*)&ApS[((tid>>5)*18 + 16)*512 + (tid&31)*8] = *(const uint2*)&xsS[tid*64 + 60];  // x0 sp
    *(uint2*)&ApP[((tid>>5)*18 + 16)*512 + (tid&31)*8] = *(const uint2*)&xsP[tid*64 + 60];  // x0 po
  }
  __syncthreads();

  // ================= decoders: dsp (A, ApS) and dcr (B, ApP), interleaved =================
  for (int t = 0; t < 16; ++t){
    // R1: [preload B_dsp] head_cr(t-1) [waves 4..7] -> ostC + x_cr(t) ; GEMM_dsp(t)
    {
      PRE4(bwDS, s0, s1, s2, s3)
      if (t > 0 && w >= 4){
        const int mt = w - 4;
        // head A-frag (16x16x32) from the 32-organized pack:
        // addr = ((mt>>1)*18 + kt*2 + (lane>>5))*512 + ((lane>>4)&1)*256 + ((mt&1)*16 + col16)*8
        const int hbase = ((mt>>1)*18 + hi5)*512 + ((quad&1)*256) + ((mt&1)*16 + col16)*8;
        f32x4 hacc = (f32x4){0.f,0.f,0.f,0.f};
        #pragma unroll
        for (int kt = 0; kt < 9; ++kt){
          bf16x8 a  = *(const bf16x8*)&ApP[hbase + kt*1024];
          bf16x8 bv = *(const bf16x8*)&headcr[((size_t)kt*64 + lane)*8];
          hacc = __builtin_amdgcn_mfma_f32_16x16x32_bf16(a, bv, hacc, 0, 0, 0);
        }
        const int s = col16;
        #pragma unroll
        for (int r = 0; r < 4; ++r){
          float v = fmaxf(hacc[r], 0.f);             // relu
          const float o = __shfl_xor(v, 1, 64);      // pair logits (lanes 4<->5)
          const int m = mt*16 + quad*4 + r;
          if (s < 4){
            ApP[((m>>5)*18 + 16)*512 + (m&31)*8 + s] = f2bf(v);  // x_cr(t) feedback
          } else if (s < 6){
            const float mx = fmaxf(v, o);
            const float e0 = __expf(v-mx), e1 = __expf(o-mx);
            ostC[m*32 + (t-1)*2 + (s-4)] = e0*rcp_(e0+e1);       // softmax2 at t-1
          }
        }
      }
      gate_gemm(aS, bwDS, acc, s0, s1, s2, s3);
    }
    __syncthreads();
    // R2: [preload B_dcr] gates_dsp(t)+wb -> ApS ; GEMM_dcr(t)
    {
      PRE4(bwDC, s0, s1, s2, s3)
      gates_wb(acc, cwA, ApS, wbBase, hi5);
      gate_gemm(aP, bwDC, acc, s0, s1, s2, s3);
    }
    __syncthreads();
    // R3: gates_dcr(t)+wb -> ApP ; head_sp(t) [waves 0..3] -> ostS + x_sp(t+1)
    gates_wb(acc, cwB, ApP, wbBase, hi5);
    if (w < 4){
      const int mt = w;
      const int hbase = ((mt>>1)*18 + hi5)*512 + ((quad&1)*256) + ((mt&1)*16 + col16)*8;
      f32x4 hacc = (f32x4){0.f,0.f,0.f,0.f};
      #pragma unroll
      for (int kt = 0; kt < 9; ++kt){
        bf16x8 a  = *(const bf16x8*)&ApS[hbase + kt*1024];
        bf16x8 bv = *(const bf16x8*)&headsp[((size_t)kt*64 + lane)*8];
        hacc = __builtin_amdgcn_mfma_f32_16x16x32_bf16(a, bv, hacc, 0, 0, 0);
      }
      const int s = col16;
      if (s < 4){
        #pragma unroll
        for (int r = 0; r < 4; ++r){
          float v = fminf(fmaxf(hacc[r], -100.f), 100.f);      // hardtanh(+-100)
          const int m = mt*16 + quad*4 + r;
          ostS[m*64 + t*4 + s] = v;
          ApS[((m>>5)*18 + 16)*512 + (m&31)*8 + s] = f2bf(v);  // x_sp(t+1) feedback
        }
      }
    }
    __syncthreads();
  }
  // ---- decoder epilogue: head_cr(15) ----
  if (w >= 4){
    const int mt = w - 4;
    const int hbase = ((mt>>1)*18 + hi5)*512 + ((quad&1)*256) + ((mt&1)*16 + col16)*8;
    f32x4 hacc = (f32x4){0.f,0.f,0.f,0.f};
    #pragma unroll
    for (int kt = 0; kt < 9; ++kt){
      bf16x8 a  = *(const bf16x8*)&ApP[hbase + kt*1024];
      bf16x8 bv = *(const bf16x8*)&headcr[((size_t)kt*64 + lane)*8];
      hacc = __builtin_amdgcn_mfma_f32_16x16x32_bf16(a, bv, hacc, 0, 0, 0);
    }
    const int s = col16;
    if (s >= 4 && s < 6){
      #pragma unroll
      for (int r = 0; r < 4; ++r){
        float v = fmaxf(hacc[r], 0.f);
        const float o = __shfl_xor(v, 1, 64);
        const int m = mt*16 + quad*4 + r;
        const float mx = fmaxf(v, o);
        const float e0 = __expf(v-mx), e1 = __expf(o-mx);
        ostC[m*32 + 15*2 + (s-4)] = e0*rcp_(e0+e1);
      }
    }
  }
  __syncthreads();

  // ---- coalesced output flush ----
  for (int i = tid; i < 4096; i += 512){
    const int oi = (brow0 + (i>>6))*64 + (i&63);
    const float v = ostS[i];
    if (f32) outf[oi] = v; else outu[oi] = f2bf(v);
  }
  for (int i = tid; i < 2048; i += 512){
    const int oi = 1048576 + (brow0 + (i>>5))*32 + (i&31);
    const float v = ostC[i];
    if (f32) outf[oi] = v; else outu[oi] = f2bf(v);
  }
}

extern "C" void kernel_launch(void* const* d_in, const int* in_sizes, int n_in,
                              void* d_out, int out_size, void* d_ws, size_t ws_size,
                              hipStream_t stream) {
  PackArgs pa;
  pa.wih[0]=(const ushort_t*)d_in[2];  pa.whh[0]=(const ushort_t*)d_in[3];
  pa.bih[0]=(const ushort_t*)d_in[4];  pa.bhh[0]=(const ushort_t*)d_in[5];
  pa.wih[1]=(const ushort_t*)d_in[6];  pa.whh[1]=(const ushort_t*)d_in[7];
  pa.bih[1]=(const ushort_t*)d_in[8];  pa.bhh[1]=(const ushort_t*)d_in[9];
  pa.wih[2]=(const ushort_t*)d_in[10]; pa.whh[2]=(const ushort_t*)d_in[11];
  pa.bih[2]=(const ushort_t*)d_in[12]; pa.bhh[2]=(const ushort_t*)d_in[13];
  pa.wih[3]=(const ushort_t*)d_in[14]; pa.whh[3]=(const ushort_t*)d_in[15];
  pa.bih[3]=(const ushort_t*)d_in[16]; pa.bhh[3]=(const ushort_t*)d_in[17];
  pa.fcsp_w=(const ushort_t*)d_in[18]; pa.fcsp_b=(const ushort_t*)d_in[19];
  pa.fccr_w=(const ushort_t*)d_in[20]; pa.fccr_b=(const ushort_t*)d_in[21];
  pa.emb_w =(const ushort_t*)d_in[22]; pa.emb_b =(const ushort_t*)d_in[23];
  pa.ws = (ushort_t*)d_ws;

  hipLaunchKernelGGL(pack_kernel, dim3((PACK_TOTAL + 255)/256), dim3(256), 0, stream, pa);
  hipLaunchKernelGGL(pvlstm_main, dim3(256), dim3(512), 0, stream,
      (const ushort_t*)d_ws,
      (const ushort_t*)d_in[0], (const ushort_t*)d_in[1],
      d_out);
}

// Round 11
// 827.729 us; speedup vs baseline: 1.0993x; 1.0993x over previous
//
#include <hip/hip_runtime.h>

typedef unsigned short ushort_t;
typedef __bf16 bf16x8 __attribute__((ext_vector_type(8)));
typedef float f32x4 __attribute__((ext_vector_type(4)));

#define PACK_W_ELEMS (8*9*8*512)           // 294912 bf16 per LSTM: [wave8][kt9][gu8][512]
#define HEAD_ELEMS   (9*512)               // 1 n-tile x 9 k-tiles
#define PACK_TOTAL   (4*PACK_W_ELEMS + 2*HEAD_ELEMS)
#define FLAG_OFS     PACK_TOTAL            // ushort index of int dtype flag

__device__ __forceinline__ float bf2f(ushort_t u){ return __uint_as_float(((unsigned)u)<<16); }
__device__ __forceinline__ ushort_t f2bf(float f){
  __bf16 h = (__bf16)f;                    // HW RTNE convert (values bounded)
  return *(ushort_t*)&h;
}
__device__ __forceinline__ float rcp_(float x){ return __builtin_amdgcn_rcpf(x); }

__device__ __forceinline__ int sniff_f32(const ushort_t* w){
  int f32 = 0;
  #pragma unroll
  for (int i = 0; i < 32; ++i){
    float f = bf2f(w[2*i]);
    if (!(f > -8.f && f < 8.f)) f32 = 1;
  }
  return f32;
}
__device__ __forceinline__ float ldin(const ushort_t* p, int i, int f32){
  return f32 ? ((const float*)p)[i] : bf2f(p[i]);
}
__device__ __forceinline__ ushort_t ldw(const ushort_t* p, int i, int f32){
  return f32 ? f2bf(((const float*)p)[i]) : p[i];
}

// ---------------- pack kernel ----------------
// Per-LSTM pack: [wave8][kt9][gu8][512]; tile (wv,kt,g,u) = B-frag of n-tile
// ntg = g*16 + wv*2 + u.  K map: k<256 Whh, 256..259 Wih, k==260 bias row (bih+bhh), else 0.
struct PackArgs {
  const ushort_t* wih[4]; const ushort_t* whh[4];
  const ushort_t* bih[4]; const ushort_t* bhh[4];
  const ushort_t* fcsp_w; const ushort_t* fcsp_b;
  const ushort_t* fccr_w; const ushort_t* fccr_b;
  const ushort_t* emb_w;  const ushort_t* emb_b;
  ushort_t* ws;
};

__global__ void pack_kernel(PackArgs a){
  const int f32 = sniff_f32(a.whh[0]);
  int idx = blockIdx.x*256 + threadIdx.x;
  if (blockIdx.x == 0 && threadIdx.x == 0) *(int*)(a.ws + FLAG_OFS) = f32;
  const int total_w = 4*PACK_W_ELEMS;
  if (idx < total_w){
    int l = idx / PACK_W_ELEMS;
    int r = idx % PACK_W_ELEMS;
    int j = r & 7;
    int lane = (r>>3) & 63;
    int tile = r >> 9;            // (wv*9 + kt)*8 + gu
    int gu = tile & 7;
    int kt = (tile >> 3) % 9;
    int wv = tile / 72;
    int g = gu >> 1, u = gu & 1;
    int n = (g*16 + wv*2 + u)*16 + (lane & 15);
    int k = kt*32 + ((lane>>4)<<3) + j;
    ushort_t v = 0;
    if (k < 256)       v = ldw(a.whh[l], n*256 + k, f32);
    else if (k < 260)  v = ldw(a.wih[l], n*4 + (k-256), f32);
    else if (k == 260) v = f2bf(ldin(a.bih[l], n, f32) + ldin(a.bhh[l], n, f32));
    a.ws[l*PACK_W_ELEMS + r] = v;
    return;
  }
  idx -= total_w;
  if (idx < 2*HEAD_ELEMS){
    int which = idx / HEAD_ELEMS;           // 0 = speed, 1 = cross
    int r = idx % HEAD_ELEMS;
    int j = r & 7; int lane = (r>>3)&63; int kt = r>>9;
    int n = lane & 15; int k = kt*32 + ((lane>>4)<<3) + j;
    ushort_t v = 0;
    if (which == 0){
      if (n < 4){
        if (k < 256)       v = ldw(a.fcsp_w, n*256 + k, f32);
        else if (k == 260) v = f2bf(ldin(a.fcsp_b, n, f32));
      }
    } else {
      if (n < 4){
        if (k < 256)       v = ldw(a.emb_w, n*256 + k, f32);
        else if (k == 260) v = f2bf(ldin(a.emb_b, n, f32));
      } else if (n < 6){
        if (k < 256)       v = ldw(a.fccr_w, (n-4)*256 + k, f32);
        else if (k == 260) v = f2bf(ldin(a.fccr_b, n-4, f32));
      }
    }
    a.ws[total_w + idx] = v;
  }
}

// ---------------- device helpers for the main kernel ----------------
// Round-0 software-pipelined gate GEMM; first half-kt B group preloaded by the caller
// (PRE4) so region-entry load latency hides under the preceding gate-VALU (r7, neutral).
#define PRE4(bw, s0, s1, s2, s3)                \
  bf16x8 s0 = *(const bf16x8*)&(bw)[0*512];     \
  bf16x8 s1 = *(const bf16x8*)&(bw)[1*512];     \
  bf16x8 s2 = *(const bf16x8*)&(bw)[2*512];     \
  bf16x8 s3 = *(const bf16x8*)&(bw)[3*512];

__device__ __forceinline__ void gate_gemm(const ushort_t* __restrict__ Aln,   // ApX + lane*8
                                          const ushort_t* __restrict__ bw,   // wave pack + lane*8
                                          f32x4 (&acc)[4][8], int lane,
                                          bf16x8 p0, bf16x8 p1, bf16x8 p2, bf16x8 p3){
  #pragma unroll
  for (int i = 0; i < 4; ++i)
    #pragma unroll
    for (int j = 0; j < 8; ++j) acc[i][j] = (f32x4){0.f,0.f,0.f,0.f};
  const ushort_t* bp = bw;
  #pragma unroll 1
  for (int kt = 0; kt < 9; ++kt){
    // load half1 of this kt (gu 4..7) — consumed after half0's MFMAs
    bf16x8 q0 = *(const bf16x8*)&bp[4*512];
    bf16x8 q1 = *(const bf16x8*)&bp[5*512];
    bf16x8 q2 = *(const bf16x8*)&bp[6*512];
    bf16x8 q3 = *(const bf16x8*)&bp[7*512];
    bf16x8 a0 = *(const bf16x8*)&Aln[(0*9+kt)*512];
    bf16x8 a1 = *(const bf16x8*)&Aln[(1*9+kt)*512];
    bf16x8 a2 = *(const bf16x8*)&Aln[(2*9+kt)*512];
    bf16x8 a3 = *(const bf16x8*)&Aln[(3*9+kt)*512];
    // MFMA half0 (gu 0..3) on the preloaded group
    acc[0][0] = __builtin_amdgcn_mfma_f32_16x16x32_bf16(a0, p0, acc[0][0], 0, 0, 0);
    acc[1][0] = __builtin_amdgcn_mfma_f32_16x16x32_bf16(a1, p0, acc[1][0], 0, 0, 0);
    acc[2][0] = __builtin_amdgcn_mfma_f32_16x16x32_bf16(a2, p0, acc[2][0], 0, 0, 0);
    acc[3][0] = __builtin_amdgcn_mfma_f32_16x16x32_bf16(a3, p0, acc[3][0], 0, 0, 0);
    acc[0][1] = __builtin_amdgcn_mfma_f32_16x16x32_bf16(a0, p1, acc[0][1], 0, 0, 0);
    acc[1][1] = __builtin_amdgcn_mfma_f32_16x16x32_bf16(a1, p1, acc[1][1], 0, 0, 0);
    acc[2][1] = __builtin_amdgcn_mfma_f32_16x16x32_bf16(a2, p1, acc[2][1], 0, 0, 0);
    acc[3][1] = __builtin_amdgcn_mfma_f32_16x16x32_bf16(a3, p1, acc[3][1], 0, 0, 0);
    acc[0][2] = __builtin_amdgcn_mfma_f32_16x16x32_bf16(a0, p2, acc[0][2], 0, 0, 0);
    acc[1][2] = __builtin_amdgcn_mfma_f32_16x16x32_bf16(a1, p2, acc[1][2], 0, 0, 0);
    acc[2][2] = __builtin_amdgcn_mfma_f32_16x16x32_bf16(a2, p2, acc[2][2], 0, 0, 0);
    acc[3][2] = __builtin_amdgcn_mfma_f32_16x16x32_bf16(a3, p2, acc[3][2], 0, 0, 0);
    acc[0][3] = __builtin_amdgcn_mfma_f32_16x16x32_bf16(a0, p3, acc[0][3], 0, 0, 0);
    acc[1][3] = __builtin_amdgcn_mfma_f32_16x16x32_bf16(a1, p3, acc[1][3], 0, 0, 0);
    acc[2][3] = __builtin_amdgcn_mfma_f32_16x16x32_bf16(a2, p3, acc[2][3], 0, 0, 0);
    acc[3][3] = __builtin_amdgcn_mfma_f32_16x16x32_bf16(a3, p3, acc[3][3], 0, 0, 0);
    // prefetch half0 of next kt (hidden under half1's MFMAs)
    if (kt < 8){
      p0 = *(const bf16x8*)&bp[4096 + 0*512];
      p1 = *(const bf16x8*)&bp[4096 + 1*512];
      p2 = *(const bf16x8*)&bp[4096 + 2*512];
      p3 = *(const bf16x8*)&bp[4096 + 3*512];
    }
    // MFMA half1 (gu 4..7)
    acc[0][4] = __builtin_amdgcn_mfma_f32_16x16x32_bf16(a0, q0, acc[0][4], 0, 0, 0);
    acc[1][4] = __builtin_amdgcn_mfma_f32_16x16x32_bf16(a1, q0, acc[1][4], 0, 0, 0);
    acc[2][4] = __builtin_amdgcn_mfma_f32_16x16x32_bf16(a2, q0, acc[2][4], 0, 0, 0);
    acc[3][4] = __builtin_amdgcn_mfma_f32_16x16x32_bf16(a3, q0, acc[3][4], 0, 0, 0);
    acc[0][5] = __builtin_amdgcn_mfma_f32_16x16x32_bf16(a0, q1, acc[0][5], 0, 0, 0);
    acc[1][5] = __builtin_amdgcn_mfma_f32_16x16x32_bf16(a1, q1, acc[1][5], 0, 0, 0);
    acc[2][5] = __builtin_amdgcn_mfma_f32_16x16x32_bf16(a2, q1, acc[2][5], 0, 0, 0);
    acc[3][5] = __builtin_amdgcn_mfma_f32_16x16x32_bf16(a3, q1, acc[3][5], 0, 0, 0);
    acc[0][6] = __builtin_amdgcn_mfma_f32_16x16x32_bf16(a0, q2, acc[0][6], 0, 0, 0);
    acc[1][6] = __builtin_amdgcn_mfma_f32_16x16x32_bf16(a1, q2, acc[1][6], 0, 0, 0);
    acc[2][6] = __builtin_amdgcn_mfma_f32_16x16x32_bf16(a2, q2, acc[2][6], 0, 0, 0);
    acc[3][6] = __builtin_amdgcn_mfma_f32_16x16x32_bf16(a3, q2, acc[3][6], 0, 0, 0);
    acc[0][7] = __builtin_amdgcn_mfma_f32_16x16x32_bf16(a0, q3, acc[0][7], 0, 0, 0);
    acc[1][7] = __builtin_amdgcn_mfma_f32_16x16x32_bf16(a1, q3, acc[1][7], 0, 0, 0);
    acc[2][7] = __builtin_amdgcn_mfma_f32_16x16x32_bf16(a2, q3, acc[2][7], 0, 0, 0);
    acc[3][7] = __builtin_amdgcn_mfma_f32_16x16x32_bf16(a3, q3, acc[3][7], 0, 0, 0);
    bp += 4096;
  }
}

// gate nonlinearity + h writeback; acc idx: i->u, f->2+u, g->4+u, o->6+u.
// Merged-division form (7 transcendentals/elem instead of 10):
//   di=1+e^-i, df=1+e^-f, dg=1+e^-2g, ng=1-e^-2g
//   cn = (c*di*dg + ng*df) / (df*di*dg)        [== sigm(f)*c + sigm(i)*tanh(g)]
//   hn = (1-e^-2cn) / ((1+e^-o)*(1+e^-2cn))    [== sigm(o)*tanh(cn)]
// Exponent args bounded (|preact| < ~40 << 88) so no overflow path.
__device__ __forceinline__ void gates_wb(f32x4 (&acc)[4][8], float (&cw)[4][2][4],
                                         ushort_t* __restrict__ Ap, int wbBase){
  #pragma unroll
  for (int mt = 0; mt < 4; ++mt)
    #pragma unroll
    for (int u = 0; u < 2; ++u)
      #pragma unroll
      for (int r = 0; r < 4; ++r){
        const float i_ = acc[mt][u][r];
        const float f_ = acc[mt][2+u][r];
        const float g_ = acc[mt][4+u][r];
        const float o_ = acc[mt][6+u][r];
        const float ei = __expf(-i_);
        const float ef = __expf(-f_);
        const float eg = __expf(-2.0f*g_);
        const float di = 1.0f + ei, df = 1.0f + ef;
        const float dg = 1.0f + eg, ng = 1.0f - eg;
        const float dig = di*dg;
        const float cn = (cw[mt][u][r]*dig + ng*df) * rcp_(df*dig);
        const float eo = __expf(-o_);
        const float ec = __expf(-2.0f*cn);
        const float hn = (1.0f - ec) * rcp_((1.0f + eo)*(1.0f + ec));
        cw[mt][u][r] = cn;
        Ap[mt*4608 + u*256 + r*8 + wbBase] = f2bf(hn);
      }
}

// ---------------- main kernel: 256 blocks x 64 rows, 512 threads (8 waves) ----------------
// Round-0/7 structure + merged-division gate math (r9, best measured: 819us).
__global__ __launch_bounds__(512, 2) void pvlstm_main(
    const ushort_t* __restrict__ ws,
    const ushort_t* __restrict__ speed,
    const ushort_t* __restrict__ pos,
    void* __restrict__ outv)
{
  __shared__ ushort_t ApS[4*9*512];   // A-pack speed-enc / speed-dec (36 KB)
  __shared__ ushort_t ApP[4*9*512];   // A-pack pos-enc / cross-dec   (36 KB)
  __shared__ ushort_t xsS[64*64];     // staged speed inputs (8 KB)
  __shared__ ushort_t xsP[64*64];     // staged pos inputs   (8 KB)
  __shared__ float    ostS[64*64];    // speed outputs stage (16 KB)
  __shared__ float    ostC[64*32];    // crossing outputs stage (8 KB)

  const int f32   = *(const int*)(ws + FLAG_OFS);
  const int tid   = threadIdx.x;
  const int lane  = tid & 63;
  const int w     = tid >> 6;   // 0..7
  const int col16 = lane & 15;
  const int quad  = lane >> 4;
  const int brow0 = blockIdx.x * 64;
  const int wbBase = w*512 + (col16>>3)*128 + quad*32 + (col16&7);

  ushort_t* outu = (ushort_t*)outv;
  float*    outf = (float*)outv;

  const ushort_t* headsp = ws + 4*PACK_W_ELEMS;
  const ushort_t* headcr = headsp + HEAD_ELEMS;
  const ushort_t* aS  = ApS + lane*8;
  const ushort_t* aP  = ApP + lane*8;
  const ushort_t* bwS  = ws + 0*PACK_W_ELEMS + (size_t)w*36864 + (size_t)lane*8;
  const ushort_t* bwP  = ws + 1*PACK_W_ELEMS + (size_t)w*36864 + (size_t)lane*8;
  const ushort_t* bwDS = ws + 2*PACK_W_ELEMS + (size_t)w*36864 + (size_t)lane*8;
  const ushort_t* bwDC = ws + 3*PACK_W_ELEMS + (size_t)w*36864 + (size_t)lane*8;

  float cwA[4][2][4], cwB[4][2][4];
  f32x4 acc[4][8];

  // ---- prologue: stage inputs, zero A-packs, bias column, x_sp(0) ----
  for (int i = tid; i < 4096; i += 512){
    int gi = (brow0 + (i>>6))*64 + (i&63);
    xsS[i] = f2bf(ldin(speed, gi, f32));
    xsP[i] = f2bf(ldin(pos,   gi, f32));
  }
  for (int i = tid; i < 4*9*512/2; i += 512){
    ((unsigned*)ApS)[i] = 0u; ((unsigned*)ApP)[i] = 0u;
  }
  #pragma unroll
  for (int mt = 0; mt < 4; ++mt)
    #pragma unroll
    for (int u = 0; u < 2; ++u)
      #pragma unroll
      for (int r = 0; r < 4; ++r){ cwA[mt][u][r] = 0.f; cwB[mt][u][r] = 0.f; }
  __syncthreads();
  if (tid < 64){
    ushort_t* xpS = &ApS[((tid>>4)*9 + 8)*512 + (tid&15)*8];
    ushort_t* xpP = &ApP[((tid>>4)*9 + 8)*512 + (tid&15)*8];
    *(uint2*)xpS = *(const uint2*)&xsS[tid*64];    // x_sp(0)
    xpS[4] = (ushort_t)0x3f80;                     // bias 1.0 column
    xpP[4] = (ushort_t)0x3f80;
  }
  __syncthreads();

  // ================= encoders: sp (A) and po (B), interleaved =================
  for (int t = 0; t < 16; ++t){
    // R1: [preload B_sp] gates_po(t-1)+wb -> ApP ; x_po(t) -> ApP.kt8 ; GEMM_sp(t)
    {
      PRE4(bwS, s0, s1, s2, s3)
      if (t > 0) gates_wb(acc, cwB, ApP, wbBase);
      if (tid < 64)
        *(uint2*)&ApP[((tid>>4)*9 + 8)*512 + (tid&15)*8] = *(const uint2*)&xsP[tid*64 + t*4];
      gate_gemm(aS, bwS, acc, lane, s0, s1, s2, s3);
    }
    __syncthreads();
    // R2: [preload B_po] gates_sp(t)+wb -> ApS ; x_sp(t+1) -> ApS.kt8 ; GEMM_po(t)
    {
      PRE4(bwP, s0, s1, s2, s3)
      gates_wb(acc, cwA, ApS, wbBase);
      if (t < 15 && tid < 64)
        *(uint2*)&ApS[((tid>>4)*9 + 8)*512 + (tid&15)*8] = *(const uint2*)&xsS[tid*64 + t*4 + 4];
      gate_gemm(aP, bwP, acc, lane, s0, s1, s2, s3);
    }
    __syncthreads();
  }
  // ---- encoder epilogue: gates_po(15) (merged form); h0 = h_sp+h_po; c0 in regs ----
  #pragma unroll
  for (int mt = 0; mt < 4; ++mt)
    #pragma unroll
    for (int u = 0; u < 2; ++u)
      #pragma unroll
      for (int r = 0; r < 4; ++r){
        const float i_ = acc[mt][u][r];
        const float f_ = acc[mt][2+u][r];
        const float g_ = acc[mt][4+u][r];
        const float o_ = acc[mt][6+u][r];
        const float ei = __expf(-i_);
        const float ef = __expf(-f_);
        const float eg = __expf(-2.0f*g_);
        const float di = 1.0f + ei, df = 1.0f + ef;
        const float dg = 1.0f + eg, ng = 1.0f - eg;
        const float dig = di*dg;
        const float cn = (cwB[mt][u][r]*dig + ng*df) * rcp_(df*dig);
        const float eo = __expf(-o_);
        const float ec = __expf(-2.0f*cn);
        const float hn = (1.0f - ec) * rcp_((1.0f + eo)*(1.0f + ec));
        const float c0 = cwA[mt][u][r] + cn;
        cwA[mt][u][r] = c0; cwB[mt][u][r] = c0;
        const int ad = mt*4608 + u*256 + r*8 + wbBase;
        ushort_t h0 = f2bf(bf2f(ApS[ad]) + hn);    // own value written in R2(15)
        ApS[ad] = h0; ApP[ad] = h0;
      }
  if (tid < 64){
    *(uint2*)&ApS[((tid>>4)*9 + 8)*512 + (tid&15)*8] = *(const uint2*)&xsS[tid*64 + 60];  // x0 sp
    *(uint2*)&ApP[((tid>>4)*9 + 8)*512 + (tid&15)*8] = *(const uint2*)&xsP[tid*64 + 60];  // x0 po
  }
  __syncthreads();

  // ================= decoders: dsp (A, ApS) and dcr (B, ApP), interleaved =================
  for (int t = 0; t < 16; ++t){
    // R1: [preload B_dsp] head_cr(t-1) [waves 4..7] -> ostC + x_cr(t) ; GEMM_dsp(t)
    {
      PRE4(bwDS, s0, s1, s2, s3)
      if (t > 0 && w >= 4){
        const int mt = w - 4;
        f32x4 hacc = (f32x4){0.f,0.f,0.f,0.f};
        #pragma unroll
        for (int kt = 0; kt < 9; ++kt){
          bf16x8 a  = *(const bf16x8*)&aP[(mt*9+kt)*512];
          bf16x8 bv = *(const bf16x8*)&headcr[((size_t)kt*64 + lane)*8];
          hacc = __builtin_amdgcn_mfma_f32_16x16x32_bf16(a, bv, hacc, 0, 0, 0);
        }
        const int s = col16;
        #pragma unroll
        for (int r = 0; r < 4; ++r){
          float v = fmaxf(hacc[r], 0.f);             // relu
          const float o = __shfl_xor(v, 1, 64);      // pair logits (lanes 4<->5)
          const int m = mt*16 + quad*4 + r;
          if (s < 4){
            ApP[(mt*9+8)*512 + (m&15)*8 + s] = f2bf(v);          // x_cr(t) feedback
          } else if (s < 6){
            const float mx = fmaxf(v, o);
            const float e0 = __expf(v-mx), e1 = __expf(o-mx);
            ostC[m*32 + (t-1)*2 + (s-4)] = e0*rcp_(e0+e1);       // softmax2 at t-1
          }
        }
      }
      gate_gemm(aS, bwDS, acc, lane, s0, s1, s2, s3);
    }
    __syncthreads();
    // R2: [preload B_dcr] gates_dsp(t)+wb -> ApS ; GEMM_dcr(t)
    {
      PRE4(bwDC, s0, s1, s2, s3)
      gates_wb(acc, cwA, ApS, wbBase);
      gate_gemm(aP, bwDC, acc, lane, s0, s1, s2, s3);
    }
    __syncthreads();
    // R3: gates_dcr(t)+wb -> ApP ; head_sp(t) [waves 0..3] -> ostS + x_sp(t+1)
    gates_wb(acc, cwB, ApP, wbBase);
    if (w < 4){
      const int mt = w;
      f32x4 hacc = (f32x4){0.f,0.f,0.f,0.f};
      #pragma unroll
      for (int kt = 0; kt < 9; ++kt){
        bf16x8 a  = *(const bf16x8*)&aS[(mt*9+kt)*512];
        bf16x8 bv = *(const bf16x8*)&headsp[((size_t)kt*64 + lane)*8];
        hacc = __builtin_amdgcn_mfma_f32_16x16x32_bf16(a, bv, hacc, 0, 0, 0);
      }
      const int s = col16;
      if (s < 4){
        #pragma unroll
        for (int r = 0; r < 4; ++r){
          float v = fminf(fmaxf(hacc[r], -100.f), 100.f);      // hardtanh(+-100)
          const int m = mt*16 + quad*4 + r;
          ostS[m*64 + t*4 + s] = v;
          ApS[(mt*9+8)*512 + (m&15)*8 + s] = f2bf(v);          // x_sp(t+1) feedback
        }
      }
    }
    __syncthreads();
  }
  // ---- decoder epilogue: head_cr(15) ----
  if (w >= 4){
    const int mt = w - 4;
    f32x4 hacc = (f32x4){0.f,0.f,0.f,0.f};
    #pragma unroll
    for (int kt = 0; kt < 9; ++kt){
      bf16x8 a  = *(const bf16x8*)&aP[(mt*9+kt)*512];
      bf16x8 bv = *(const bf16x8*)&headcr[((size_t)kt*64 + lane)*8];
      hacc = __builtin_amdgcn_mfma_f32_16x16x32_bf16(a, bv, hacc, 0, 0, 0);
    }
    const int s = col16;
    if (s >= 4 && s < 6){
      #pragma unroll
      for (int r = 0; r < 4; ++r){
        float v = fmaxf(hacc[r], 0.f);
        const float o = __shfl_xor(v, 1, 64);
        const int m = mt*16 + quad*4 + r;
        const float mx = fmaxf(v, o);
        const float e0 = __expf(v-mx), e1 = __expf(o-mx);
        ostC[m*32 + 15*2 + (s-4)] = e0*rcp_(e0+e1);
      }
    }
  }
  __syncthreads();

  // ---- coalesced output flush ----
  for (int i = tid; i < 4096; i += 512){
    const int oi = (brow0 + (i>>6))*64 + (i&63);
    const float v = ostS[i];
    if (f32) outf[oi] = v; else outu[oi] = f2bf(v);
  }
  for (int i = tid; i < 2048; i += 512){
    const int oi = 1048576 + (brow0 + (i>>5))*32 + (i&31);
    const float v = ostC[i];
    if (f32) outf[oi] = v; else outu[oi] = f2bf(v);
  }
}

extern "C" void kernel_launch(void* const* d_in, const int* in_sizes, int n_in,
                              void* d_out, int out_size, void* d_ws, size_t ws_size,
                              hipStream_t stream) {
  PackArgs pa;
  pa.wih[0]=(const ushort_t*)d_in[2];  pa.whh[0]=(const ushort_t*)d_in[3];
  pa.bih[0]=(const ushort_t*)d_in[4];  pa.bhh[0]=(const ushort_t*)d_in[5];
  pa.wih[1]=(const ushort_t*)d_in[6];  pa.whh[1]=(const ushort_t*)d_in[7];
  pa.bih[1]=(const ushort_t*)d_in[8];  pa.bhh[1]=(const ushort_t*)d_in[9];
  pa.wih[2]=(const ushort_t*)d_in[10]; pa.whh[2]=(const ushort_t*)d_in[11];
  pa.bih[2]=(const ushort_t*)d_in[12]; pa.bhh[2]=(const ushort_t*)d_in[13];
  pa.wih[3]=(const ushort_t*)d_in[14]; pa.whh[3]=(const ushort_t*)d_in[15];
  pa.bih[3]=(const ushort_t*)d_in[16]; pa.bhh[3]=(const ushort_t*)d_in[17];
  pa.fcsp_w=(const ushort_t*)d_in[18]; pa.fcsp_b=(const ushort_t*)d_in[19];
  pa.fccr_w=(const ushort_t*)d_in[20]; pa.fccr_b=(const ushort_t*)d_in[21];
  pa.emb_w =(const ushort_t*)d_in[22]; pa.emb_b =(const ushort_t*)d_in[23];
  pa.ws = (ushort_t*)d_ws;

  hipLaunchKernelGGL(pack_kernel, dim3((PACK_TOTAL + 255)/256), dim3(256), 0, stream, pa);
  hipLaunchKernelGGL(pvlstm_main, dim3(256), dim3(512), 0, stream,
      (const ushort_t*)d_ws,
      (const ushort_t*)d_in[0], (const ushort_t*)d_in[1],
      d_out);
}